// Round 5
// baseline (206.374 us; speedup 1.0000x reference)
//
#include <hip/hip_runtime.h>
#include <hip/hip_fp16.h>

// Problem constants: B=16, N=128, H=128, BD=64, P=256
using f16x4 = __attribute__((ext_vector_type(4))) _Float16;
using f32x4 = __attribute__((ext_vector_type(4))) float;

__device__ __forceinline__ f16x4 ld_f16x4(const void* p) {
    return *reinterpret_cast<const f16x4*>(p);
}

// ---------------------------------------------------------------------------
// Prep kernel A: W2bt[p][k] = W2[128+k][p] (f16, transposed, row=64 f16), and
// W3 -> W3s (f16, [p][k] transposed, chunked by 32-k, XOR-swizzled: within
// each 64B row the 16B group g sits at g^(p&3), so LDS reads are ~conflict-
// free after a LINEAR copy into LDS).
// ---------------------------------------------------------------------------
__global__ void sp_wconv(const float* __restrict__ W2, const float* __restrict__ W3,
                         _Float16* __restrict__ W2bt, _Float16* __restrict__ W3s) {
    int t = blockIdx.x * 256 + threadIdx.x;   // grid covers 65536
    if (t < 16384) {
        int p = t >> 6, k = t & 63;
        W2bt[t] = (_Float16)W2[(128 + k) * 256 + p];
    }
    {
        // W3s flat index t -> (kc, p, slot', e); inverse swizzle: s = s' ^ (p&3)
        int kc = t >> 13, rem = t & 8191;
        int p = rem >> 5, q = rem & 31;
        int sp_ = q >> 3, e = q & 7;
        int s = sp_ ^ (p & 3);
        int k = kc * 32 + s * 8 + e;
        W3s[t] = (_Float16)W3[k * 256 + p];
    }
}

// ---------------------------------------------------------------------------
// Prep kernel B: hpart[b*128+j][p] = hid[b,j,:] @ W2[0:128,p] + b2[p]  (fp32,
// natural row-major: sp_main lanes read 4 consecutive p as one float4).
// ---------------------------------------------------------------------------
__global__ void sp_hpart(const float* __restrict__ hs, const float* __restrict__ W2,
                         const float* __restrict__ b2, float* __restrict__ hpart) {
    __shared__ float sh[8 * 128];
    int rb = blockIdx.x * 8;
    int tid = threadIdx.x;
    for (int t = tid; t < 1024; t += 256) sh[t] = hs[rb * 128 + t];
    __syncthreads();
    float acc[8];
    float bb = b2[tid];
#pragma unroll
    for (int r = 0; r < 8; ++r) acc[r] = bb;
    for (int k = 0; k < 128; ++k) {
        float w = W2[k * 256 + tid];
#pragma unroll
        for (int r = 0; r < 8; ++r) acc[r] += sh[r * 128 + k] * w;
    }
#pragma unroll
    for (int r = 0; r < 8; ++r) hpart[(rb + r) * 256 + tid] = acc[r];
}

// ---------------------------------------------------------------------------
// Main kernel: one block per (b,i). 4 waves, wave w owns j in [32w,32w+32).
// mfma_f32_16x16x16f16 throughout (A[m=l%16][k=4*(l/16)+e], B[k][n=l%16],
// D[m=4*(l/16)+r][n=l%16]).
//
// KEY: first GEMM computed TRANSPOSED: acc = W2bt(A, M=p) x enc(B, N=j)
//  -> lane holds D[p = pt*16+4lk+r][j = wave*32+jt*16+l15].
// That is exactly the A-frag layout of the second GEMM
//  (A[m=j=l15][k=p=4lk+e], k-step index = pt), so U = relu(acc + hpart)
// stays entirely IN REGISTERS (f16) — no U staging, no scalar LDS writes.
// Second GEMM: emb = U @ W3, K=256 in 8 chunks of 32; W3 chunks double-
// buffered in LDS (reg-staged: loads issued before compute, ds_write after).
// pooled[p] = max_{j != i} emb[j,p] + b3[p] -> d_out row bi (write-only).
// LDS: 2x16KB W3 dbuf + 4KB pool = 36KB. VGPR-bound ~2 blocks/CU.
// ---------------------------------------------------------------------------
__global__ __launch_bounds__(256, 2) void sp_main(
    const float* __restrict__ pos, const float* __restrict__ W1,
    const float* __restrict__ b1, const float* __restrict__ b3,
    const float* __restrict__ hpart, const _Float16* __restrict__ W2bt,
    const _Float16* __restrict__ W3s, float* __restrict__ pool) {
    __shared__ __align__(16) char sW3[2][16384];
    __shared__ float sPool[1024];

    const int bi = blockIdx.x;
    const int b = bi >> 7, i = bi & 127;
    const int tid = threadIdx.x;
    const int wave = tid >> 6, lane = tid & 63;
    const int l15 = lane & 15, lk = lane >> 4;

    const float pix = pos[(b * 128 + i) * 2 + 0];
    const float piy = pos[(b * 128 + i) * 2 + 1];

    // --- enc as B-fragments: B[k = s*16+4lk+e][n=j], j = wave*32+jt*16+l15 --
    f16x4 benc[2][4];
#pragma unroll
    for (int jt = 0; jt < 2; ++jt) {
        int j = wave * 32 + jt * 16 + l15;
        float rx = pos[(b * 128 + j) * 2 + 0] - pix;
        float ry = pos[(b * 128 + j) * 2 + 1] - piy;
#pragma unroll
        for (int s = 0; s < 4; ++s) {
            int k0 = s * 16 + lk * 4;
            f16x4 v;
#pragma unroll
            for (int e = 0; e < 4; ++e) {
                int k = k0 + e;
                float t = rx * W1[k] + ry * W1[64 + k] + b1[k];
                v[e] = (_Float16)(t > 0.f ? t : 0.f);
            }
            benc[jt][s] = v;
        }
    }

    // --- first GEMM (transposed): acc[jt][pt] = D[p][j] -------------------
    f32x4 acc[2][16];
#pragma unroll
    for (int jt = 0; jt < 2; ++jt)
#pragma unroll
        for (int pt = 0; pt < 16; ++pt) acc[jt][pt] = (f32x4){0.f, 0.f, 0.f, 0.f};

#pragma unroll
    for (int s = 0; s < 4; ++s) {
        int k0 = s * 16 + lk * 4;
#pragma unroll
        for (int pt = 0; pt < 16; ++pt) {
            int p = pt * 16 + l15;
            f16x4 aw = ld_f16x4(W2bt + p * 64 + k0);   // A[m=p][k]
            acc[0][pt] = __builtin_amdgcn_mfma_f32_16x16x16f16(aw, benc[0][s], acc[0][pt], 0, 0, 0);
            acc[1][pt] = __builtin_amdgcn_mfma_f32_16x16x16f16(aw, benc[1][s], acc[1][pt], 0, 0, 0);
        }
    }

    // --- U = relu(acc + hpart[j]) -> f16 A-frags, in registers ------------
    // lane holds (p = pt*16+4lk+r, j = wave*32+jt*16+l15)
    f16x4 u[2][16];
#pragma unroll
    for (int jt = 0; jt < 2; ++jt) {
        int j = wave * 32 + jt * 16 + l15;
        const float* hprow = hpart + (b * 128 + j) * 256 + lk * 4;
#pragma unroll
        for (int pt = 0; pt < 16; ++pt) {
            f32x4 hp = *reinterpret_cast<const f32x4*>(hprow + pt * 16);
            f16x4 v;
#pragma unroll
            for (int r = 0; r < 4; ++r) {
                float t = acc[jt][pt][r] + hp[r];
                v[r] = (_Float16)(t > 0.f ? t : 0.f);
            }
            u[jt][pt] = v;
        }
    }

    // --- second GEMM: emb = U @ W3, K=256, 8 chunks of 32, LDS dbuf -------
    f32x4 eacc[2][16];
#pragma unroll
    for (int jt = 0; jt < 2; ++jt)
#pragma unroll
        for (int pt = 0; pt < 16; ++pt) eacc[jt][pt] = (f32x4){0.f, 0.f, 0.f, 0.f};

    const uint4* W3v = (const uint4*)W3s;   // 1024 uint4 per 16KB chunk
    {
        // prologue: stage chunk 0 into buf 0
        uint4 g0[4];
#pragma unroll
        for (int it = 0; it < 4; ++it) g0[it] = W3v[tid + it * 256];
#pragma unroll
        for (int it = 0; it < 4; ++it) ((uint4*)sW3[0])[tid + it * 256] = g0[it];
    }
    __syncthreads();

#pragma unroll
    for (int kc = 0; kc < 8; ++kc) {
        const int buf = kc & 1;
        uint4 g[4];
        if (kc < 7) {   // issue next-chunk loads early (overlap with MFMA)
            const uint4* src = W3v + (kc + 1) * 1024;
#pragma unroll
            for (int it = 0; it < 4; ++it) g[it] = src[tid + it * 256];
        }
#pragma unroll
        for (int s2 = 0; s2 < 2; ++s2) {
            const int ks = kc * 2 + s2;            // k-step = u's pt index
#pragma unroll
            for (int pt = 0; pt < 16; ++pt) {
                int p = pt * 16 + l15;
                int gidx = (2 * s2 + (lk >> 1)) ^ (p & 3);   // swizzled 16B group
                f16x4 bf = ld_f16x4(sW3[buf] + p * 64 + gidx * 16 + (lk & 1) * 8);
                eacc[0][pt] = __builtin_amdgcn_mfma_f32_16x16x16f16(u[0][ks], bf, eacc[0][pt], 0, 0, 0);
                eacc[1][pt] = __builtin_amdgcn_mfma_f32_16x16x16f16(u[1][ks], bf, eacc[1][pt], 0, 0, 0);
            }
        }
        if (kc < 7) {   // write-late: land next chunk into the other buffer
            uint4* dst = (uint4*)sW3[buf ^ 1];
#pragma unroll
            for (int it = 0; it < 4; ++it) dst[tid + it * 256] = g[it];
        }
        __syncthreads();
    }

    // --- masked max over j, cross-lane + cross-wave reduce ----------------
    // eacc: row j = wave*32 + jt*16 + 4lk + r, col p = pt*16 + l15
    float pm[16];
#pragma unroll
    for (int pt = 0; pt < 16; ++pt) {
        float m = -INFINITY;
#pragma unroll
        for (int jt = 0; jt < 2; ++jt) {
#pragma unroll
            for (int r = 0; r < 4; ++r) {
                int row = wave * 32 + jt * 16 + lk * 4 + r;
                float v = eacc[jt][pt][r];
                if (row != i) m = fmaxf(m, v);
            }
        }
        m = fmaxf(m, __shfl_xor(m, 16));
        m = fmaxf(m, __shfl_xor(m, 32));
        pm[pt] = m;
    }
    if (lane < 16) {
#pragma unroll
        for (int pt = 0; pt < 16; ++pt) sPool[wave * 256 + pt * 16 + lane] = pm[pt];
    }
    __syncthreads();
    {
        float v = fmaxf(fmaxf(sPool[tid], sPool[256 + tid]),
                        fmaxf(sPool[512 + tid], sPool[768 + tid]));
        pool[bi * 256 + tid] = v + b3[tid];    // d_out row bi (write-only)
    }
}

// ---------------------------------------------------------------------------
// Final: io = io @ Wout + bout, IN PLACE on d_out (16 rows per block; all 16
// rows staged to LDS behind a barrier before any write -> in-place safe).
// ---------------------------------------------------------------------------
__global__ void sp_out(const float* __restrict__ Wout, const float* __restrict__ bout,
                       float* __restrict__ io) {
    __shared__ float sp[16 * 256];
    int rb = blockIdx.x * 16;
    int tid = threadIdx.x;
    for (int t = tid; t < 4096; t += 256) sp[t] = io[rb * 256 + t];
    __syncthreads();
    float acc[16];
    float bb = bout[tid];
#pragma unroll
    for (int r = 0; r < 16; ++r) acc[r] = bb;
    for (int k = 0; k < 256; ++k) {
        float w = Wout[k * 256 + tid];
#pragma unroll
        for (int r = 0; r < 16; ++r) acc[r] += sp[r * 256 + k] * w;
    }
#pragma unroll
    for (int r = 0; r < 16; ++r) io[(rb + r) * 256 + tid] = acc[r];
}

extern "C" void kernel_launch(void* const* d_in, const int* in_sizes, int n_in,
                              void* d_out, int out_size, void* d_ws, size_t ws_size,
                              hipStream_t stream) {
    const float* hs   = (const float*)d_in[0];
    const float* pos  = (const float*)d_in[1];
    const float* W1   = (const float*)d_in[2];
    const float* b1   = (const float*)d_in[3];
    const float* W2   = (const float*)d_in[4];
    const float* b2   = (const float*)d_in[5];
    const float* W3   = (const float*)d_in[6];
    const float* b3   = (const float*)d_in[7];
    const float* Wout = (const float*)d_in[8];
    const float* bout = (const float*)d_in[9];
    float* out = (float*)d_out;

    // ws layout: hpart 2MB | W2bt 32KB | W3s 128KB  (~2.2MB total)
    float*    hpart = (float*)d_ws;
    _Float16* W2bt  = (_Float16*)((char*)d_ws + (1 << 21));
    _Float16* W3s   = (_Float16*)((char*)d_ws + (1 << 21) + 32768);

    sp_wconv<<<256, 256, 0, stream>>>(W2, W3, W2bt, W3s);
    sp_hpart<<<256, 256, 0, stream>>>(hs, W2, b2, hpart);
    sp_main<<<2048, 256, 0, stream>>>(pos, W1, b1, b3, hpart, W2bt, W3s, out);
    sp_out<<<128, 256, 0, stream>>>(Wout, bout, out);
}

// Round 6
// 179.728 us; speedup vs baseline: 1.1483x; 1.1483x over previous
//
#include <hip/hip_runtime.h>
#include <hip/hip_fp16.h>

// Problem constants: B=16, N=128, H=128, BD=64, P=256
using f16x4 = __attribute__((ext_vector_type(4))) _Float16;
using f32x4 = __attribute__((ext_vector_type(4))) float;

__device__ __forceinline__ f16x4 ld_f16x4(const void* p) {
    return *reinterpret_cast<const f16x4*>(p);
}

// ---------------------------------------------------------------------------
// Prep kernel A: W2bt[p][k] = W2[128+k][p] (f16 transposed, 64 f16/row), and
// W3 -> W3s: f16, row = p' (output col, 0..255), 32 k per row (64B), chunked
// by kc (32 k each). Within-row byte order is chosen so reader lane (l15,lk)
// gets k = s2*16 + lk*4 + e from byte gidx*16 + (lk&1)*8 + e*2 with
// gidx = 2*s2 + (lk>>1).
// ---------------------------------------------------------------------------
__global__ void sp_wconv(const float* __restrict__ W2, const float* __restrict__ W3,
                         _Float16* __restrict__ W2bt, _Float16* __restrict__ W3s) {
    int t = blockIdx.x * 256 + threadIdx.x;   // grid covers 65536
    if (t < 16384) {
        int p = t >> 6, k = t & 63;
        W2bt[t] = (_Float16)W2[(128 + k) * 256 + p];
    }
    {
        int kc = t >> 13, rem = t & 8191;
        int prow = rem >> 5, inrow = rem & 31;   // f16 index within 64B row
        int gidx = inrow >> 3, within = inrow & 7;
        int lklo = within >> 2, e = within & 3;
        int s2 = gidx >> 1, lkhi = gidx & 1;
        int k = kc * 32 + s2 * 16 + (lkhi * 2 + lklo) * 4 + e;
        W3s[t] = (_Float16)W3[k * 256 + prow];
    }
}

// ---------------------------------------------------------------------------
// Prep kernel B: hp16[b*128+j][p] = hid[b,j,:] @ W2[0:128,p] + b2[p]  (f16)
// ---------------------------------------------------------------------------
__global__ void sp_hpart(const float* __restrict__ hs, const float* __restrict__ W2,
                         const float* __restrict__ b2, _Float16* __restrict__ hp16) {
    __shared__ float sh[8 * 128];
    int rb = blockIdx.x * 8;
    int tid = threadIdx.x;
    for (int t = tid; t < 1024; t += 256) sh[t] = hs[rb * 128 + t];
    __syncthreads();
    float acc[8];
    float bb = b2[tid];
#pragma unroll
    for (int r = 0; r < 8; ++r) acc[r] = bb;
    for (int k = 0; k < 128; ++k) {
        float w = W2[k * 256 + tid];
#pragma unroll
        for (int r = 0; r < 8; ++r) acc[r] += sh[r * 128 + k] * w;
    }
#pragma unroll
    for (int r = 0; r < 8; ++r) hp16[(rb + r) * 256 + tid] = (_Float16)acc[r];
}

// ---------------------------------------------------------------------------
// Main kernel: one block per (b,i). 4 waves, wave w owns j in [32w,32w+32).
// mfma_f32_16x16x16f16 (A[m=l%16][k=4*(l/16)+e], B[k][n=l%16],
// D[m=4*(l/16)+r][n=l%16]).
//   u[jt][pt] preloaded with hp16 (f16x4 gathers, latency hidden by GEMM1)
//   GEMM1 transposed per-pt: acc = W2bt(A,M=p) x enc(B,N=j); immediately
//     u[jt][pt] = relu(acc + hp) in registers (A-frags of GEMM2, k-index=pt)
//   GEMM2 in TWO p'-passes (eacc[2][8] = 64 regs): emb = U @ W3, K=256 in
//     8 chunks of 32; per pass stage 128 p'-rows x 32k into LDS rows padded
//     to 80B (20 banks -> phase-conflict-free b64 reads), double-buffered,
//     loads issued before MFMA cluster, ds_write after (T14).
//   pooled[p'] = max_{j != i} emb[j,p'] + b3[p'] -> d_out row bi (write-only)
// LDS: 2 x 10KB W3 + 4KB pool = 24.5KB; target 3 blocks/CU via VGPR<=170.
// ---------------------------------------------------------------------------
__global__ __launch_bounds__(256, 3) void sp_main(
    const float* __restrict__ pos, const float* __restrict__ W1,
    const float* __restrict__ b1, const float* __restrict__ b3,
    const _Float16* __restrict__ hp16, const _Float16* __restrict__ W2bt,
    const _Float16* __restrict__ W3s, float* __restrict__ pool) {
    __shared__ __align__(16) char sW3[2][10240];   // 128 rows x 80B each
    __shared__ float sPool[1024];

    const int bi = blockIdx.x;
    const int b = bi >> 7, i = bi & 127;
    const int tid = threadIdx.x;
    const int wave = tid >> 6, lane = tid & 63;
    const int l15 = lane & 15, lk = lane >> 4;

    // --- u preload: hp16 rows for this lane's two j's, all 16 p-tiles ------
    f16x4 u[2][16];
#pragma unroll
    for (int jt = 0; jt < 2; ++jt) {
        int j = wave * 32 + jt * 16 + l15;
        const _Float16* hprow = hp16 + (b * 128 + j) * 256 + lk * 4;
#pragma unroll
        for (int pt = 0; pt < 16; ++pt) u[jt][pt] = ld_f16x4(hprow + pt * 16);
    }

    const float pix = pos[(b * 128 + i) * 2 + 0];
    const float piy = pos[(b * 128 + i) * 2 + 1];

    // --- W1/b1 vectorized (each lane's fixed 16 k-slots) -------------------
    f32x4 w1x[4], w1y[4], bb1[4];
#pragma unroll
    for (int s = 0; s < 4; ++s) {
        int k0 = s * 16 + lk * 4;
        w1x[s] = *reinterpret_cast<const f32x4*>(W1 + k0);
        w1y[s] = *reinterpret_cast<const f32x4*>(W1 + 64 + k0);
        bb1[s] = *reinterpret_cast<const f32x4*>(b1 + k0);
    }

    // --- enc as B-fragments: B[k=s*16+4lk+e][n=j] ---------------------------
    f16x4 benc[2][4];
#pragma unroll
    for (int jt = 0; jt < 2; ++jt) {
        int j = wave * 32 + jt * 16 + l15;
        float rx = pos[(b * 128 + j) * 2 + 0] - pix;
        float ry = pos[(b * 128 + j) * 2 + 1] - piy;
#pragma unroll
        for (int s = 0; s < 4; ++s) {
            f16x4 v;
#pragma unroll
            for (int e = 0; e < 4; ++e) {
                float t = fmaf(rx, w1x[s][e], fmaf(ry, w1y[s][e], bb1[s][e]));
                v[e] = (_Float16)(t > 0.f ? t : 0.f);
            }
            benc[jt][s] = v;
        }
    }

    // --- GEMM1 (transposed) per-pt + in-register U build -------------------
#pragma unroll
    for (int pt = 0; pt < 16; ++pt) {
        f32x4 a0 = (f32x4){0.f, 0.f, 0.f, 0.f};
        f32x4 a1 = (f32x4){0.f, 0.f, 0.f, 0.f};
#pragma unroll
        for (int s = 0; s < 4; ++s) {
            f16x4 aw = ld_f16x4(W2bt + (pt * 16 + l15) * 64 + s * 16 + lk * 4);
            a0 = __builtin_amdgcn_mfma_f32_16x16x16f16(aw, benc[0][s], a0, 0, 0, 0);
            a1 = __builtin_amdgcn_mfma_f32_16x16x16f16(aw, benc[1][s], a1, 0, 0, 0);
        }
        // lane holds D[p = pt*16+4lk+r][j = wave*32+jt*16+l15]
        {
            f16x4 hp = u[0][pt], v;
#pragma unroll
            for (int r = 0; r < 4; ++r) {
                float t = a0[r] + (float)hp[r];
                v[r] = (_Float16)(t > 0.f ? t : 0.f);
            }
            u[0][pt] = v;
        }
        {
            f16x4 hp = u[1][pt], v;
#pragma unroll
            for (int r = 0; r < 4; ++r) {
                float t = a1[r] + (float)hp[r];
                v[r] = (_Float16)(t > 0.f ? t : 0.f);
            }
            u[1][pt] = v;
        }
    }

    // --- GEMM2: emb = U @ W3, two p'-passes, 8 k-chunks each, LDS dbuf -----
    const uint4* W3v = (const uint4*)W3s;   // 1024 uint4 per chunk; 512/half
#pragma unroll
    for (int pass = 0; pass < 2; ++pass) {
        f32x4 eacc[2][8];
#pragma unroll
        for (int jt = 0; jt < 2; ++jt)
#pragma unroll
            for (int pt = 0; pt < 8; ++pt) eacc[jt][pt] = (f32x4){0.f, 0.f, 0.f, 0.f};

        {   // prologue: stage (pass, kc=0) into buf 0 (padded scatter)
            uint4 g0 = W3v[pass * 512 + tid];
            uint4 g1 = W3v[pass * 512 + 256 + tid];
            int q0 = tid, q1 = tid + 256;
            *(uint4*)(sW3[0] + (q0 >> 2) * 80 + (q0 & 3) * 16) = g0;
            *(uint4*)(sW3[0] + (q1 >> 2) * 80 + (q1 & 3) * 16) = g1;
        }
        __syncthreads();

#pragma unroll
        for (int kc = 0; kc < 8; ++kc) {
            const int buf = kc & 1;
            uint4 g0, g1;
            if (kc < 7) {   // issue next half-chunk loads early
                const uint4* src = W3v + (kc + 1) * 1024 + pass * 512;
                g0 = src[tid];
                g1 = src[tid + 256];
            }
#pragma unroll
            for (int s2 = 0; s2 < 2; ++s2) {
                const int ks = kc * 2 + s2;
#pragma unroll
                for (int pt = 0; pt < 8; ++pt) {
                    f16x4 bf = ld_f16x4(sW3[buf] + (pt * 16 + l15) * 80 +
                                        (2 * s2 + (lk >> 1)) * 16 + (lk & 1) * 8);
                    eacc[0][pt] = __builtin_amdgcn_mfma_f32_16x16x16f16(u[0][ks], bf, eacc[0][pt], 0, 0, 0);
                    eacc[1][pt] = __builtin_amdgcn_mfma_f32_16x16x16f16(u[1][ks], bf, eacc[1][pt], 0, 0, 0);
                }
            }
            if (kc < 7) {   // write-late into the other buffer
                int q0 = tid, q1 = tid + 256;
                *(uint4*)(sW3[buf ^ 1] + (q0 >> 2) * 80 + (q0 & 3) * 16) = g0;
                *(uint4*)(sW3[buf ^ 1] + (q1 >> 2) * 80 + (q1 & 3) * 16) = g1;
            }
            __syncthreads();
        }

        // --- masked max over this wave's 32 j, reduce across lane groups ---
#pragma unroll
        for (int pt = 0; pt < 8; ++pt) {
            float m = -INFINITY;
#pragma unroll
            for (int jt = 0; jt < 2; ++jt) {
#pragma unroll
                for (int r = 0; r < 4; ++r) {
                    int row = wave * 32 + jt * 16 + lk * 4 + r;
                    float v = eacc[jt][pt][r];
                    if (row != i) m = fmaxf(m, v);
                }
            }
            m = fmaxf(m, __shfl_xor(m, 16));
            m = fmaxf(m, __shfl_xor(m, 32));
            if (lane < 16) sPool[wave * 256 + (pass * 8 + pt) * 16 + lane] = m;
        }
    }
    __syncthreads();
    {
        float v = fmaxf(fmaxf(sPool[tid], sPool[256 + tid]),
                        fmaxf(sPool[512 + tid], sPool[768 + tid]));
        pool[bi * 256 + tid] = v + b3[tid];    // d_out row bi (write-only)
    }
}

// ---------------------------------------------------------------------------
// Final: io = io @ Wout + bout, IN PLACE on d_out (8 rows per block; rows
// staged to LDS behind a barrier before any write -> in-place safe).
// ---------------------------------------------------------------------------
__global__ void sp_out(const float* __restrict__ Wout, const float* __restrict__ bout,
                       float* __restrict__ io) {
    __shared__ float sp[8 * 256];
    int rb = blockIdx.x * 8;
    int tid = threadIdx.x;
    for (int t = tid; t < 2048; t += 256) sp[t] = io[rb * 256 + t];
    __syncthreads();
    float acc[8];
    float bb = bout[tid];
#pragma unroll
    for (int r = 0; r < 8; ++r) acc[r] = bb;
    for (int k = 0; k < 256; ++k) {
        float w = Wout[k * 256 + tid];
#pragma unroll
        for (int r = 0; r < 8; ++r) acc[r] += sp[r * 256 + k] * w;
    }
#pragma unroll
    for (int r = 0; r < 8; ++r) io[(rb + r) * 256 + tid] = acc[r];
}

extern "C" void kernel_launch(void* const* d_in, const int* in_sizes, int n_in,
                              void* d_out, int out_size, void* d_ws, size_t ws_size,
                              hipStream_t stream) {
    const float* hs   = (const float*)d_in[0];
    const float* pos  = (const float*)d_in[1];
    const float* W1   = (const float*)d_in[2];
    const float* b1   = (const float*)d_in[3];
    const float* W2   = (const float*)d_in[4];
    const float* b2   = (const float*)d_in[5];
    const float* W3   = (const float*)d_in[6];
    const float* b3   = (const float*)d_in[7];
    const float* Wout = (const float*)d_in[8];
    const float* bout = (const float*)d_in[9];
    float* out = (float*)d_out;

    // ws layout: hp16 1MB | W2bt 32KB | W3s 128KB  (~1.2MB total)
    _Float16* hp16 = (_Float16*)d_ws;
    _Float16* W2bt = (_Float16*)((char*)d_ws + (1 << 20));
    _Float16* W3s  = (_Float16*)((char*)d_ws + (1 << 20) + 32768);

    sp_wconv<<<256, 256, 0, stream>>>(W2, W3, W2bt, W3s);
    sp_hpart<<<256, 256, 0, stream>>>(hs, W2, b2, hp16);
    sp_main<<<2048, 256, 0, stream>>>(pos, W1, b1, b3, hp16, W2bt, W3s, out);
    sp_out<<<256, 256, 0, stream>>>(Wout, bout, out);
}